// Round 7
// baseline (286.865 us; speedup 1.0000x reference)
//
#include <hip/hip_runtime.h>
#include <math.h>
#include <stdint.h>

typedef __attribute__((ext_vector_type(8))) short bf16x8;
typedef __attribute__((ext_vector_type(4))) float floatx4;

static __device__ __forceinline__ unsigned short f32_to_bf16_rne(float f) {
    union { float f; uint32_t u; } v; v.f = f;
    uint32_t u = v.u;
    return (unsigned short)((u + 0x7fffu + ((u >> 16) & 1u)) >> 16);
}
static __device__ __forceinline__ float bf16_to_f32(unsigned short h) {
    union { uint32_t u; float f; } v; v.u = ((uint32_t)h) << 16;
    return v.f;
}
static __device__ __forceinline__ uint32_t pack2(float2 a) {
    return (uint32_t)f32_to_bf16_rne(a.x) | ((uint32_t)f32_to_bf16_rne(a.y) << 16);
}

// LDS-correct barrier that does NOT drain vmcnt (keeps global prefetch in
// flight). lgkmcnt(0) before s_barrier makes this wave's ds_writes visible;
// memory clobbers stop the compiler moving LDS ops across it.
#define BARRIER() do { \
    asm volatile("s_waitcnt lgkmcnt(0)" ::: "memory"); \
    __builtin_amdgcn_s_barrier(); \
    asm volatile("" ::: "memory"); } while (0)

// ---------------------------------------------------------------------------
// Prep: W1a (50x318) -> hi/lo bf16, fragment-ordered:
// byte = ks*8192 + p*4096 + kq*1024 + n*16  (n in [0,64), zero-padded)
// ---------------------------------------------------------------------------
__global__ void prep_w(const float* __restrict__ W1a, unsigned short* __restrict__ Bpre) {
    int idx = blockIdx.x * 256 + threadIdx.x;
    if (idx >= 40960) return;
    int e  = idx & 7;
    int n  = (idx >> 3) & 63;
    int kq = (idx >> 9) & 3;
    int p  = (idx >> 11) & 1;
    int ks = idx >> 12;
    int k  = ks * 32 + kq * 8 + e;
    float w = (n < 50 && k < 318) ? W1a[n * 318 + k] : 0.0f;
    unsigned short hi = f32_to_bf16_rne(w);
    Bpre[idx] = (p == 0) ? hi : f32_to_bf16_rne(w - bf16_to_f32(hi));
}

// ---------------------------------------------------------------------------
// Kernel A (persistent): 512 blocks x 16 slabs (64 tokens each), 256 threads.
// B hi/lo fragments register-resident (80 VGPR, loaded once). Per iteration:
// pack prefetched regs -> LDS A-planes, issue next slab's loads (stay in
// flight across raw barriers), 80 MFMA, tail. h2 overlays dead plane space.
// ---------------------------------------------------------------------------
#define A_STR 336                 // bytes per row within a K-plane
#define PLANE 21504               // bytes per K-plane (64 rows)
#define H1_OFF 43008              // h1: [64][54] f32
#define H1S 54
#define H3_OFF 56832              // h3: [64][22] f32
#define H3S 22
#define H2S 22                    // h2 overlays plane region (offset 0)
#define SLAB (64 * 318)

__global__ __launch_bounds__(256, 2)
void fused_mlp(const float* __restrict__ x,
               const unsigned short* __restrict__ Bpre,
               const float* __restrict__ b1a,
               const float* __restrict__ W1b, const float* __restrict__ b1b,
               const float* __restrict__ W1c, const float* __restrict__ b1c,
               const float* __restrict__ pW1, const float* __restrict__ pb1,
               const float* __restrict__ pW2, const float* __restrict__ pb2,
               float* __restrict__ partials)
{
    __shared__ __align__(16) char smem[62464];

    const int tid  = threadIdx.x;
    const int wv   = tid >> 6;
    const int lane = tid & 63;
    const int fr   = lane & 15;
    const int kq   = lane >> 4;
    const int row  = tid >> 2;      // staging: 4 threads per token row
    const int q    = tid & 3;

    const float* rowp = x + (size_t)blockIdx.x * 16 * SLAB + row * 318 + 2 * q;
    char* wrow = smem + row * A_STR + q * 4;

    // ---- B hi/lo fragments, register-resident for all 16 slabs
    bf16x8 Bh[10], Bl[10];
    {
        const char* bb = (const char*)Bpre + (kq << 10) + ((wv * 16 + fr) << 4);
        #pragma unroll
        for (int ks = 0; ks < 10; ++ks) {
            Bh[ks] = *(const bf16x8*)(bb + ks * 8192);
            Bl[ks] = *(const bf16x8*)(bb + ks * 8192 + 4096);
        }
    }

    // ---- prologue: issue slab-0 loads (both K-planes)
    float2 ga[40];
    #pragma unroll
    for (int j = 0; j < 20; ++j) ga[j] = *(const float2*)(rowp + 8 * j);
    #pragma unroll
    for (int j = 0; j < 20; ++j) {
        bool pad = (q == 3) && (j == 19);            // k = 318,319
        ga[20 + j] = pad ? make_float2(0.f, 0.f)
                         : *(const float2*)(rowp + 160 + 8 * j);
    }

    #pragma unroll 1
    for (int it = 0; it < 16; ++it) {
        // ---- S1: pack prefetched regs -> planes (vmcnt via reg deps)
        #pragma unroll
        for (int j = 0; j < 20; ++j)
            *(uint32_t*)(wrow + 16 * j) = pack2(ga[j]);
        #pragma unroll
        for (int j = 0; j < 20; ++j)
            *(uint32_t*)(wrow + PLANE + 16 * j) = pack2(ga[20 + j]);
        // ---- issue next slab's loads; they stay in flight across barriers
        if (it < 15) {
            const float* np = rowp + (size_t)(it + 1) * SLAB;
            #pragma unroll
            for (int j = 0; j < 20; ++j) ga[j] = *(const float2*)(np + 8 * j);
            #pragma unroll
            for (int j = 0; j < 20; ++j) {
                bool pad = (q == 3) && (j == 19);
                ga[20 + j] = pad ? make_float2(0.f, 0.f)
                                 : *(const float2*)(np + 160 + 8 * j);
            }
        }
        BARRIER();   // planes ready

        // ---- S2: 10 K-steps x 4 m-frags, hi+lo MFMA
        floatx4 acc[4];
        #pragma unroll
        for (int mi = 0; mi < 4; ++mi) acc[mi] = (floatx4){0.f, 0.f, 0.f, 0.f};
        #pragma unroll
        for (int ks = 0; ks < 10; ++ks) {
            const char* ab = smem + (ks < 5 ? 0 : PLANE) + fr * A_STR
                           + (ks < 5 ? ks : ks - 5) * 64 + kq * 16;
            #pragma unroll
            for (int mi = 0; mi < 4; ++mi) {
                bf16x8 a = *(const bf16x8*)(ab + mi * (16 * A_STR));
                acc[mi] = __builtin_amdgcn_mfma_f32_16x16x32_bf16(a, Bh[ks], acc[mi], 0, 0, 0);
                acc[mi] = __builtin_amdgcn_mfma_f32_16x16x32_bf16(a, Bl[ks], acc[mi], 0, 0, 0);
            }
        }

        // ---- S3: bias + ReLU -> h1 [64][54] f32 (dedicated region)
        {
            const int n = wv * 16 + fr;
            float* h1 = (float*)(smem + H1_OFF);
            if (n < 50) {
                float bia = b1a[n];
                #pragma unroll
                for (int mi = 0; mi < 4; ++mi)
                    #pragma unroll
                    for (int r = 0; r < 4; ++r)
                        h1[(mi * 16 + kq * 4 + r) * H1S + n] = fmaxf(acc[mi][r] + bia, 0.0f);
            }
        }
        BARRIER();   // h1 ready (and all plane reads done)

        // ---- S4: layer2 (50->20), wave w -> outputs [5w,5w+5); h2 overlays planes
        {
            const float* h1r = (const float*)(smem + H1_OFF) + lane * H1S;
            float* h2b = (float*)smem;
            #pragma unroll
            for (int oo = 0; oo < 5; ++oo) {
                int o = wv * 5 + oo;
                float a = b1b[o];
                const float* w = W1b + o * 50;
                #pragma unroll
                for (int i = 0; i < 50; ++i) a = fmaf(h1r[i], w[i], a);
                h2b[lane * H2S + o] = fmaxf(a, 0.0f);
            }
        }
        BARRIER();   // h2 ready

        // ---- S5: layer3 (20->20), wave w -> outputs [5w,5w+5)
        {
            float h2v[20];
            const float2* h2r = (const float2*)((float*)smem + lane * H2S);
            #pragma unroll
            for (int i2 = 0; i2 < 10; ++i2) {
                float2 u = h2r[i2];
                h2v[2 * i2] = u.x; h2v[2 * i2 + 1] = u.y;
            }
            float* h3b = (float*)(smem + H3_OFF);
            #pragma unroll
            for (int oo = 0; oo < 5; ++oo) {
                int o = wv * 5 + oo;
                float a = b1c[o];
                const float* w = W1c + o * 20;
                #pragma unroll
                for (int i = 0; i < 20; ++i) a = fmaf(h2v[i], w[i], a);
                h3b[lane * H3S + o] = fmaxf(a, 0.0f);
            }
        }
        BARRIER();   // h3 ready

        // ---- S6: all waves compute score+softmax partial (redundant), wv0 writes
        {
            float h3v[20];
            const float2* h3r = (const float2*)((float*)(smem + H3_OFF) + lane * H3S);
            #pragma unroll
            for (int i2 = 0; i2 < 10; ++i2) {
                float2 u = h3r[i2];
                h3v[2 * i2] = u.x; h3v[2 * i2 + 1] = u.y;
            }
            float s = pb2[0];
            #pragma unroll
            for (int j = 0; j < 10; ++j) {
                float a = pb1[j];
                const float* w = pW1 + j * 20;
                #pragma unroll
                for (int i = 0; i < 20; ++i) a = fmaf(h3v[i], w[i], a);
                s = fmaf(fmaxf(a, 0.0f), pW2[j], s);
            }

            float m = s;
            #pragma unroll
            for (int d = 32; d > 0; d >>= 1) m = fmaxf(m, __shfl_xor(m, d));
            float e = expf(s - m);
            float S = e;
            #pragma unroll
            for (int d = 32; d > 0; d >>= 1) S += __shfl_xor(S, d);

            float V[20];
            #pragma unroll
            for (int o = 0; o < 20; ++o) {
                float v = e * h3v[o];
                #pragma unroll
                for (int d = 32; d > 0; d >>= 1) v += __shfl_xor(v, d);
                V[o] = v;
            }

            if (wv == 0) {
                float myv = m;
                if (lane == 1) myv = S;
                #pragma unroll
                for (int o = 0; o < 20; ++o) if (lane == o + 2) myv = V[o];
                if (lane < 22)
                    partials[(size_t)(blockIdx.x * 16 + it) * 24 + lane] = myv;
            }
        }
        // no barrier: next S1 packs planes (h3 region untouched)
    }
}

// ---------------------------------------------------------------------------
// Kernel B: combine half-group partials, pool over G=128, normalize, head.
// ---------------------------------------------------------------------------
__global__ __launch_bounds__(128, 4)
void pool_g_head(const float* __restrict__ partials,
                 const float* __restrict__ qW1, const float* __restrict__ qb1,
                 const float* __restrict__ qW2, const float* __restrict__ qb2,
                 const float* __restrict__ W3a, const float* __restrict__ b3a,
                 const float* __restrict__ W3b, const float* __restrict__ b3b,
                 float* __restrict__ out)
{
    __shared__ float red_m[2];
    __shared__ float red_s[2];
    __shared__ float part[2][20];

    const int tid = threadIdx.x;      // g
    const int b = blockIdx.x;
    const float* P = partials + ((size_t)(b * 128 + tid)) * 48;

    float m0 = P[0], S0 = P[1], m1 = P[24], S1 = P[25];
    float m = fmaxf(m0, m1);
    float w0 = expf(m0 - m), w1 = expf(m1 - m);
    float den = fmaf(S0, w0, S1 * w1);

    float v[20];
    #pragma unroll
    for (int o = 0; o < 20; ++o)
        v[o] = fmaf(P[2 + o], w0, P[26 + o] * w1) / den;

    float s = qb2[0];
    #pragma unroll
    for (int j = 0; j < 10; ++j) {
        float a = qb1[j];
        const float* w = qW1 + j * 20;
        #pragma unroll
        for (int i = 0; i < 20; ++i) a = fmaf(v[i], w[i], a);
        s = fmaf(fmaxf(a, 0.0f), qW2[j], s);
    }

    const int wig = tid >> 6, lane = tid & 63;
    float mm = s;
    #pragma unroll
    for (int d = 32; d > 0; d >>= 1) mm = fmaxf(mm, __shfl_xor(mm, d));
    if (lane == 0) red_m[wig] = mm;
    __syncthreads();
    mm = fmaxf(red_m[0], red_m[1]);

    float e = expf(s - mm);
    float su = e;
    #pragma unroll
    for (int d = 32; d > 0; d >>= 1) su += __shfl_xor(su, d);
    if (lane == 0) red_s[wig] = su;

    #pragma unroll
    for (int o = 0; o < 20; ++o) {
        float val = e * v[o];
        #pragma unroll
        for (int d = 32; d > 0; d >>= 1) val += __shfl_xor(val, d);
        if (lane == 0) part[wig][o] = val;
    }
    __syncthreads();

    if (tid == 0) {
        float dg = red_s[0] + red_s[1];
        float rb[20];
        float n2 = 0.0f;
        #pragma unroll
        for (int o = 0; o < 20; ++o) {
            rb[o] = (part[0][o] + part[1][o]) / dg;
            n2 = fmaf(rb[o], rb[o], n2);
        }
        float nrm = fmaxf(sqrtf(n2), 1e-12f);
        #pragma unroll
        for (int o = 0; o < 20; ++o) rb[o] /= nrm;

        float accv = b3b[0];
        #pragma unroll
        for (int j = 0; j < 10; ++j) {
            float a = b3a[j];
            const float* w = W3a + j * 20;
            #pragma unroll
            for (int i = 0; i < 20; ++i) a = fmaf(rb[i], w[i], a);
            accv = fmaf(fmaxf(a, 0.0f), W3b[j], accv);
        }
        out[b] = accv;
    }
}

extern "C" void kernel_launch(void* const* d_in, const int* in_sizes, int n_in,
                              void* d_out, int out_size, void* d_ws, size_t ws_size,
                              hipStream_t stream) {
    const float* x   = (const float*)d_in[0];
    const float* W1a = (const float*)d_in[1];
    const float* b1a = (const float*)d_in[2];
    const float* W1b = (const float*)d_in[3];
    const float* b1b = (const float*)d_in[4];
    const float* W1c = (const float*)d_in[5];
    const float* b1c = (const float*)d_in[6];
    const float* pW1 = (const float*)d_in[7];
    const float* pb1 = (const float*)d_in[8];
    const float* pW2 = (const float*)d_in[9];
    const float* pb2 = (const float*)d_in[10];
    const float* qW1 = (const float*)d_in[11];
    const float* qb1 = (const float*)d_in[12];
    const float* qW2 = (const float*)d_in[13];
    const float* qb2 = (const float*)d_in[14];
    const float* W3a = (const float*)d_in[15];
    const float* b3a = (const float*)d_in[16];
    const float* W3b = (const float*)d_in[17];
    const float* b3b = (const float*)d_in[18];

    float* partials      = (float*)d_ws;                             // 786,432 B
    unsigned short* Bpre = (unsigned short*)((char*)d_ws + 786432);  // 81,920 B

    prep_w<<<160, 256, 0, stream>>>(W1a, Bpre);
    fused_mlp<<<512, 256, 0, stream>>>(
        x, Bpre, b1a, W1b, b1b, W1c, b1c, pW1, pb1, pW2, pb2, partials);
    pool_g_head<<<32, 128, 0, stream>>>(
        partials, qW1, qb1, qW2, qb2, W3a, b3a, W3b, b3b, (float*)d_out);
}